// Round 3
// baseline (113.672 us; speedup 1.0000x reference)
//
#include <hip/hip_runtime.h>
#include <cmath>

#define HH 256
#define WW 256
#define RAD 12
#define KLEN 25
#define NMAPS 512
#define ESTRIP 32
#define NSTRIP (HH / ESTRIP)     // 8
#define NITER (ESTRIP + 2)       // 34

// ---------------------------------------------------------------------------
// Kernel A: one single-wave block (64 lanes) per (map, strip); 4 cols/lane.
// Vertical conv from 25-deep float4 register ring; horizontal conv from a
// symmetric-padded double-buffered LDS row via 7 aligned ds_read_b128.
// ---------------------------------------------------------------------------
__global__ __launch_bounds__(64, 2) void blur_peak_strip(
    const float* __restrict__ in,
    float* __restrict__ sval,
    int* __restrict__ sidx,
    int* __restrict__ scnt)
{
    __shared__ __align__(16) float vrow[2][WW + 2 * RAD];  // 2 x 280 floats

    const int l     = threadIdx.x;        // lane 0..63, owns cols 4l..4l+3
    const int blk   = blockIdx.x;
    const int m     = blk >> 3;
    const int strip = blk & 7;
    const float4* map4 = reinterpret_cast<const float4*>(in) + (size_t)m * (HH * WW / 4);

    const int e0 = strip * ESTRIP;
    const int o0 = e0 - 1;

    // Gaussian coefficients, symmetric half — identical float32 math to R2.
    float kf[RAD + 1];
    {
        float s = 0.f;
#pragma unroll
        for (int i = 0; i <= RAD; ++i) {
            float t = (float)(i - RAD);
            kf[i] = expf(-(t * t) / 18.0f);
            s += (i < RAD) ? 2.f * kf[i] : kf[i];
        }
#pragma unroll
        for (int i = 0; i <= RAD; ++i) kf[i] /= s;
    }

    // Register ring, 4 scalar arrays (all indices static under full unroll).
    // After append in iter t (o=o0+t): r*[i] = padded[o+i], padded[q]=raw[mirr(q-12)]
    float rx[KLEN], ry[KLEN], rz[KLEN], rw[KLEN];
#pragma unroll
    for (int i = 1; i < KLEN; ++i) {
        int q = o0 + i - 1 - RAD;
        int r = (q < 0) ? (-q - 1) : q;           // top mirror (bottom impossible in init)
        float4 t4 = map4[(size_t)r * (WW / 4) + l];
        rx[i] = t4.x; ry[i] = t4.y; rz[i] = t4.z; rw[i] = t4.w;
    }
    rx[0] = ry[0] = rz[0] = rw[0] = 0.f;          // never read

    // g history per column (rows o, o-1, o-2)
    float g0c[4]  = {0.f, 0.f, 0.f, 0.f};
    float gm1c[4] = {0.f, 0.f, 0.f, 0.f};
    float gm2c[4] = {0.f, 0.f, 0.f, 0.f};

    float bval = -1.f;
    int   bidx = 0x7FFFFFFF;
    int   cnt  = 0;

#pragma unroll
    for (int t = 0; t < NITER; ++t) {
        const int o = o0 + t;

        // ---- append padded[o+24] (raw row o+12, bottom mirror) ----
        {
            int r = o + RAD;
            if (r > HH - 1) r = 2 * HH - 1 - r;
            float4 nv = map4[(size_t)r * (WW / 4) + l];
#pragma unroll
            for (int i = 0; i < KLEN - 1; ++i) {
                rx[i] = rx[i + 1]; ry[i] = ry[i + 1];
                rz[i] = rz[i + 1]; rw[i] = rw[i + 1];
            }
            rx[KLEN - 1] = nv.x; ry[KLEN - 1] = nv.y;
            rz[KLEN - 1] = nv.z; rw[KLEN - 1] = nv.w;
        }

        // ---- vertical conv (same pairing/order as R2) ----
        float vx = kf[RAD] * rx[RAD];
        float vy = kf[RAD] * ry[RAD];
        float vz = kf[RAD] * rz[RAD];
        float vw = kf[RAD] * rw[RAD];
#pragma unroll
        for (int d = 0; d < RAD; ++d) {
            vx += kf[d] * (rx[d] + rx[2 * RAD - d]);
            vy += kf[d] * (ry[d] + ry[2 * RAD - d]);
            vz += kf[d] * (rz[d] + rz[2 * RAD - d]);
            vw += kf[d] * (rw[d] + rw[2 * RAD - d]);
        }

        float* vr = vrow[t & 1];
        reinterpret_cast<float4*>(vr + RAD)[l] = make_float4(vx, vy, vz, vw);
        if (l < 3)   reinterpret_cast<float4*>(vr)[2 - l]   = make_float4(vw, vz, vy, vx);
        if (l >= 61) reinterpret_cast<float4*>(vr)[130 - l] = make_float4(vw, vz, vy, vx);
        __syncthreads();

        // ---- horizontal conv: lane window = padded cols 4l .. 4l+27 ----
        float w[28];
#pragma unroll
        for (int k = 0; k < 7; ++k) {
            float4 t4 = reinterpret_cast<const float4*>(vr)[l + k];
            w[4 * k + 0] = t4.x; w[4 * k + 1] = t4.y;
            w[4 * k + 2] = t4.z; w[4 * k + 3] = t4.w;
        }
        float gq[4];
#pragma unroll
        for (int q = 0; q < 4; ++q) {
            float acc = kf[RAD] * w[q + RAD];
#pragma unroll
            for (int d = 0; d < RAD; ++d) acc += kf[d] * (w[q + d] + w[q + 2 * RAD - d]);
            gq[q] = acc;
        }
        // shift history (same as R2: shift, then eval uses gm1 = g[o-1])
#pragma unroll
        for (int q = 0; q < 4; ++q) { gm2c[q] = gm1c[q]; gm1c[q] = g0c[q]; g0c[q] = gq[q]; }

        // ---- peak eval at row e = o-1 (t >= 2; folds at compile time) ----
        if (t >= 2) {
            const int e = o - 1;
            float lf0 = __shfl_up(gm1c[3], 1);   if (l == 0)  lf0 = 0.f;
            float rt3 = __shfl_down(gm1c[0], 1); if (l == 63) rt3 = 0.f;
            const bool etop = (e == 0), ebot = (e == HH - 1);
            float mvq[4] = {rx[11], ry[11], rz[11], rw[11]};   // raw row e
#pragma unroll
            for (int q = 0; q < 4; ++q) {
                float gE = gm1c[q];
                float up = etop ? 0.f : gm2c[q];
                float dn = ebot ? 0.f : g0c[q];
                float lf = (q == 0) ? lf0 : gm1c[q - 1];
                float rt = (q == 3) ? rt3 : gm1c[q + 1];
                bool pk = (gE >= up) && (gE >= dn) && (gE >= lf) && (gE >= rt) && (gE > 0.01f);
                if (pk) {
                    cnt++;
                    float mv = mvq[q];
                    int fi = e * WW + 4 * l + q;
                    if (mv > bval) { bval = mv; bidx = fi; }   // strict > keeps first
                }
            }
        }
    }

    // ---- 64-lane butterfly: (max val, min idx on tie), sum count ----
#pragma unroll
    for (int off = 32; off > 0; off >>= 1) {
        float v2 = __shfl_xor(bval, off);
        int   i2 = __shfl_xor(bidx, off);
        int   c2 = __shfl_xor(cnt,  off);
        if (v2 > bval || (v2 == bval && i2 < bidx)) { bval = v2; bidx = i2; }
        cnt += c2;
    }
    if (l == 0) { sval[blk] = bval; sidx[blk] = bidx; scnt[blk] = cnt; }
}

// ---------------------------------------------------------------------------
// Kernel B: per-map combine strips + 5x5 window sums at winner + output logic
// ---------------------------------------------------------------------------
__global__ __launch_bounds__(256) void finalize_kernel(
    const float* __restrict__ in,
    const float* __restrict__ sval,
    const int* __restrict__ sidx,
    const int* __restrict__ scnt,
    float* __restrict__ out)
{
    int t = blockIdx.x * blockDim.x + threadIdx.x;
    if (t >= NMAPS) return;

    float BV = -1.f; int BI = 0x7FFFFFFF; int C = 0;
#pragma unroll
    for (int s2 = 0; s2 < NSTRIP; ++s2) {
        int k = t * NSTRIP + s2;
        float v = sval[k]; int i = sidx[k];
        if (v > BV || (v == BV && i < BI)) { BV = v; BI = i; }
        C += scnt[k];
    }

    bool valid = (C == 1) || ((C > 1) && (BV >= 0.8f));

    float kx = -999.999f, ky = -999.999f, conf = 0.f;
    if (valid) {
        int pr = BI / WW, pc = BI % WW;
        const float* map = in + (size_t)t * HH * WW;
        float S = 0.f, SX = 0.f, SY = 0.f;
#pragma unroll
        for (int dr = -2; dr <= 2; ++dr) {
            int r = pr + dr;
            if (r < 0 || r >= HH) continue;
#pragma unroll
            for (int dc = -2; dc <= 2; ++dc) {
                int cc = pc + dc;
                if (cc < 0 || cc >= WW) continue;
                float mv = map[r * WW + cc];
                S  += mv;
                SX += mv * (float)cc;
                SY += mv * (float)r;
            }
        }
        float x = (S == 0.f) ? (float)pc : (SX / S);
        float y = (S == 0.f) ? (float)pr : (SY / S);
        kx = x + 0.4395f;
        ky = y + 0.4395f;
        conf = 1.f;
    }
    out[t * 3 + 0] = kx;
    out[t * 3 + 1] = ky;
    out[t * 3 + 2] = conf;
}

extern "C" void kernel_launch(void* const* d_in, const int* in_sizes, int n_in,
                              void* d_out, int out_size, void* d_ws, size_t ws_size,
                              hipStream_t stream) {
    const float* in = (const float*)d_in[0];
    float* out = (float*)d_out;

    const int nblk = NMAPS * NSTRIP;   // 4096
    float* sval = (float*)d_ws;
    int*   sidx = (int*)((char*)d_ws + (size_t)nblk * 4);
    int*   scnt = (int*)((char*)d_ws + (size_t)nblk * 8);

    blur_peak_strip<<<nblk, 64, 0, stream>>>(in, sval, sidx, scnt);
    finalize_kernel<<<(NMAPS + 255) / 256, 256, 0, stream>>>(in, sval, sidx, scnt, out);
}